// Round 1
// baseline (1171.970 us; speedup 1.0000x reference)
//
#include <hip/hip_runtime.h>
#include <math.h>

// CapsNet dynamic routing, fully fused. One block handles G (b,n) pairs.
// Thread t owns output column o = t (k = t>>4, d = t&15); u_hat[k][i][d]
// lives in registers r[g][i] (32 VGPR per pair). W (512 KB) streams from L2,
// amortized over G pairs per block.

#define G 4
#define IC 32
#define ID 16
#define NC 16
#define DC 16
#define O  256   // NC*DC

__global__ __launch_bounds__(256, 2)
void capsule_routing_kernel(const float* __restrict__ inp,   // [B,N,IC,ID]
                            const float* __restrict__ W,     // [IC,ID,O]
                            float* __restrict__ outp)        // [B,N,NC,DC]
{
    const int t = threadIdx.x;
    const int pair0 = blockIdx.x * G;

    __shared__ float bb[NC][IC];       // routing logits b (one pair at a time)
    __shared__ float cc[NC][IC + 1];   // softmax coeffs, +1 pad kills k-stride bank conflict
    __shared__ float sinv[IC];

    // ---- u_hat for G pairs: r[g][i] = sum_dd x_g[i][dd] * W[i][dd][t]
    float r[G][IC];
    const float* xb[G];
    #pragma unroll
    for (int g = 0; g < G; ++g)
        xb[g] = inp + (size_t)(pair0 + g) * (IC * ID);

    #pragma unroll
    for (int i = 0; i < IC; ++i) {
        float acc[G];
        #pragma unroll
        for (int g = 0; g < G; ++g) acc[g] = 0.0f;
        #pragma unroll
        for (int dd = 0; dd < ID; ++dd) {
            float w = W[(i * ID + dd) * O + t];   // coalesced; L2-resident
            #pragma unroll
            for (int g = 0; g < G; ++g)
                acc[g] = fmaf(w, xb[g][i * ID + dd], acc[g]);  // x uniform -> SGPR
        }
        #pragma unroll
        for (int g = 0; g < G; ++g) r[g][i] = acc[g];
    }

    const int k = t >> 4;
    const int d = t & 15;

    #pragma unroll
    for (int g = 0; g < G; ++g) {
        __syncthreads();                 // previous pair done with bb/cc
        ((float*)bb)[t]       = 0.0f;    // b = 0
        ((float*)bb)[t + 256] = 0.0f;
        __syncthreads();

        float out = 0.0f;
        #pragma unroll
        for (int it = 0; it < 3; ++it) {
            // c = softmax over NC axis (per i): threads 0..31 each own one i
            if (t < IC) {
                float m = -1e30f;
                #pragma unroll
                for (int kk = 0; kk < NC; ++kk) m = fmaxf(m, bb[kk][t]);
                float s = 0.0f;
                #pragma unroll
                for (int kk = 0; kk < NC; ++kk) {
                    float e = __expf(bb[kk][t] - m);
                    cc[kk][t] = e;
                    s += e;
                }
                sinv[t] = 1.0f / s;
            }
            __syncthreads();
            {   // normalize: 512 entries, 2 per thread
                int e0 = t, e1 = t + 256;
                cc[e0 >> 5][e0 & 31] *= sinv[e0 & 31];
                cc[e1 >> 5][e1 & 31] *= sinv[e1 & 31];
            }
            __syncthreads();

            // outputs[k][d] = sum_i c[k][i] * u_hat[k][i][d]
            out = 0.0f;
            #pragma unroll
            for (int i = 0; i < IC; ++i)
                out = fmaf(cc[k][i], r[g][i], out);

            if (it < 2) {
                // squash over d (16 contiguous lanes)
                float s2 = out * out;
                s2 += __shfl_xor(s2, 1);
                s2 += __shfl_xor(s2, 2);
                s2 += __shfl_xor(s2, 4);
                s2 += __shfl_xor(s2, 8);
                float scale = s2 / ((1.0f + s2) * sqrtf(s2 + 1e-7f));
                out *= scale;

                // b[k][i] += sum_d out * u_hat[k][i][d]
                #pragma unroll
                for (int i = 0; i < IC; ++i) {
                    float p = out * r[g][i];
                    p += __shfl_xor(p, 1);
                    p += __shfl_xor(p, 2);
                    p += __shfl_xor(p, 4);
                    p += __shfl_xor(p, 8);
                    if (d == 0) bb[k][i] += p;
                }
                __syncthreads();
            }
        }
        // final iteration: no squash; coalesced store
        outp[(size_t)(pair0 + g) * O + t] = out;
    }
}

extern "C" void kernel_launch(void* const* d_in, const int* in_sizes, int n_in,
                              void* d_out, int out_size, void* d_ws, size_t ws_size,
                              hipStream_t stream) {
    const float* inp = (const float*)d_in[0];   // [32,128,32,16] fp32
    const float* W   = (const float*)d_in[1];   // [32,16,256]   fp32
    float* outp      = (float*)d_out;           // [32,128,16,16] fp32

    const int npairs = 32 * 128;                // B*N = 4096
    dim3 grid(npairs / G), block(256);
    hipLaunchKernelGGL(capsule_routing_kernel, grid, block, 0, stream,
                       inp, W, outp);
}

// Round 2
// 996.238 us; speedup vs baseline: 1.1764x; 1.1764x over previous
//
#include <hip/hip_runtime.h>
#include <math.h>

// CapsNet dynamic routing, fully fused. One block handles G (b,n) pairs.
// Thread t owns output column o = t (k = t>>4, d = t&15); u_hat[k][i][d]
// lives in registers r[g][i]. G=2 keeps per-thread state ~100 VGPRs ->
// fits the 128-VGPR allocation with NO scratch spill (round-1 G=4 spilled:
// 405 MB scratch writes, 1277 us). W (512 KB) streams from L2 per block.

#define G 2
#define IC 32
#define ID 16
#define NC 16
#define DC 16
#define O  256   // NC*DC

__global__ __launch_bounds__(256, 4)
void capsule_routing_kernel(const float* __restrict__ inp,   // [B,N,IC,ID]
                            const float* __restrict__ W,     // [IC,ID,O]
                            float* __restrict__ outp)        // [B,N,NC,DC]
{
    const int t = threadIdx.x;
    const int pair0 = blockIdx.x * G;

    __shared__ float bb[NC][IC];       // routing logits b (one pair at a time)
    __shared__ float cc[NC][IC + 1];   // softmax coeffs, +1 pad kills k-stride bank conflict
    __shared__ float sinv[IC];

    // ---- u_hat for G pairs: r[g][i] = sum_dd x_g[i][dd] * W[i][dd][t]
    float r[G][IC];
    const float* xb[G];
    #pragma unroll
    for (int g = 0; g < G; ++g)
        xb[g] = inp + (size_t)(pair0 + g) * (IC * ID);

    #pragma unroll
    for (int i = 0; i < IC; ++i) {
        float acc[G];
        #pragma unroll
        for (int g = 0; g < G; ++g) acc[g] = 0.0f;
        #pragma unroll
        for (int dd = 0; dd < ID; ++dd) {
            float w = W[(i * ID + dd) * O + t];   // coalesced; L2-resident
            #pragma unroll
            for (int g = 0; g < G; ++g)
                acc[g] = fmaf(w, xb[g][i * ID + dd], acc[g]);  // x uniform -> SGPR
        }
        #pragma unroll
        for (int g = 0; g < G; ++g) r[g][i] = acc[g];
    }

    const int k = t >> 4;
    const int d = t & 15;

    #pragma unroll
    for (int g = 0; g < G; ++g) {
        __syncthreads();                 // previous pair done with bb/cc
        ((float*)bb)[t]       = 0.0f;    // b = 0
        ((float*)bb)[t + 256] = 0.0f;
        __syncthreads();

        float out = 0.0f;
        #pragma unroll
        for (int it = 0; it < 3; ++it) {
            // c = softmax over NC axis (per i): threads 0..31 each own one i
            if (t < IC) {
                float m = -1e30f;
                #pragma unroll
                for (int kk = 0; kk < NC; ++kk) m = fmaxf(m, bb[kk][t]);
                float s = 0.0f;
                #pragma unroll
                for (int kk = 0; kk < NC; ++kk) {
                    float e = __expf(bb[kk][t] - m);
                    cc[kk][t] = e;
                    s += e;
                }
                sinv[t] = 1.0f / s;
            }
            __syncthreads();
            {   // normalize: 512 entries, 2 per thread
                int e0 = t, e1 = t + 256;
                cc[e0 >> 5][e0 & 31] *= sinv[e0 & 31];
                cc[e1 >> 5][e1 & 31] *= sinv[e1 & 31];
            }
            __syncthreads();

            // outputs[k][d] = sum_i c[k][i] * u_hat[k][i][d]
            out = 0.0f;
            #pragma unroll
            for (int i = 0; i < IC; ++i)
                out = fmaf(cc[k][i], r[g][i], out);

            if (it < 2) {
                // squash over d (16 contiguous lanes)
                float s2 = out * out;
                s2 += __shfl_xor(s2, 1);
                s2 += __shfl_xor(s2, 2);
                s2 += __shfl_xor(s2, 4);
                s2 += __shfl_xor(s2, 8);
                float scale = s2 / ((1.0f + s2) * sqrtf(s2 + 1e-7f));
                out *= scale;

                // b[k][i] += sum_d out * u_hat[k][i][d]
                #pragma unroll
                for (int i = 0; i < IC; ++i) {
                    float p = out * r[g][i];
                    p += __shfl_xor(p, 1);
                    p += __shfl_xor(p, 2);
                    p += __shfl_xor(p, 4);
                    p += __shfl_xor(p, 8);
                    if (d == 0) bb[k][i] += p;
                }
                __syncthreads();
            }
        }
        // final iteration: no squash; coalesced store
        outp[(size_t)(pair0 + g) * O + t] = out;
    }
}

extern "C" void kernel_launch(void* const* d_in, const int* in_sizes, int n_in,
                              void* d_out, int out_size, void* d_ws, size_t ws_size,
                              hipStream_t stream) {
    const float* inp = (const float*)d_in[0];   // [32,128,32,16] fp32
    const float* W   = (const float*)d_in[1];   // [32,16,256]   fp32
    float* outp      = (float*)d_out;           // [32,128,16,16] fp32

    const int npairs = 32 * 128;                // B*N = 4096
    dim3 grid(npairs / G), block(256);
    hipLaunchKernelGGL(capsule_routing_kernel, grid, block, 0, stream,
                       inp, W, outp);
}

// Round 3
// 77.931 us; speedup vs baseline: 15.0386x; 12.7837x over previous
//
#include <hip/hip_runtime.h>
#include <math.h>

// CapsNet dynamic routing, fully fused, 2 (b,n) pairs per block.
// Thread t owns output column o = t (k = t>>4, d = t&15); u_hat[k][i][d]
// lives in TWO NAMED register arrays r0[i], r1[i] — never indexed by a
// runtime variable, so the compiler can promote them (rounds 1-2 used
// r[g][i] under a refused #pragma unroll -> whole array demoted to
// scratch: 0.4-1.0 GB scratch traffic, VGPR_Count 64, ~1 ms).
// Both pairs are routed simultaneously (no pair loop at all).
// Routing iteration 0 is specialized: softmax(0) = 1/16 uniform.

#define IC 32
#define ID 16
#define NC 16
#define DC 16
#define O  256   // NC*DC

__device__ __forceinline__ float reduce16(float v) {
    v += __shfl_xor(v, 1);
    v += __shfl_xor(v, 2);
    v += __shfl_xor(v, 4);
    v += __shfl_xor(v, 8);
    return v;
}

__device__ __forceinline__ float squash16(float v) {
    float s2 = v * v;
    s2 = reduce16(s2);
    float scale = s2 / ((1.0f + s2) * sqrtf(s2 + 1e-7f));
    return v * scale;
}

__global__ __launch_bounds__(256, 4)
void capsule_routing_kernel(const float* __restrict__ inp,   // [B,N,IC,ID]
                            const float* __restrict__ W,     // [IC,ID,O]
                            float* __restrict__ outp)        // [B,N,NC,DC]
{
    const int t = threadIdx.x;
    const int pair0 = blockIdx.x * 2;

    __shared__ float bb[2][NC][IC + 1];   // routing logits, pad kills k-stride conflicts
    __shared__ float cc[2][NC][IC + 1];   // softmax coeffs

    // ---- u_hat: r0[i] = sum_dd x0[i][dd]*W[i][dd][t], r1 likewise
    float r0[IC], r1[IC];
    const float* x0 = inp + (size_t)pair0 * (IC * ID);
    const float* x1 = x0 + IC * ID;

    #pragma unroll
    for (int i = 0; i < IC; ++i) {
        float a0 = 0.0f, a1 = 0.0f;
        #pragma unroll
        for (int dd = 0; dd < ID; ++dd) {
            float w = W[(i * ID + dd) * O + t];   // coalesced, L2-resident
            a0 = fmaf(w, x0[i * ID + dd], a0);    // x uniform -> scalar load
            a1 = fmaf(w, x1[i * ID + dd], a1);
        }
        r0[i] = a0;
        r1[i] = a1;
    }

    const int k = t >> 4;
    const int d = t & 15;
    float out0, out1;

    // ---- routing iter 0: b = 0 -> c = 1/16 uniform (softmax skipped)
    out0 = 0.0f; out1 = 0.0f;
    #pragma unroll
    for (int i = 0; i < IC; ++i) { out0 += r0[i]; out1 += r1[i]; }
    out0 = squash16(out0 * 0.0625f);
    out1 = squash16(out1 * 0.0625f);
    #pragma unroll
    for (int i = 0; i < IC; ++i) {        // b[k][i] = sum_d out[k][d]*u_hat[k][i][d]
        float p0 = reduce16(out0 * r0[i]);
        float p1 = reduce16(out1 * r1[i]);
        if (d == 0) { bb[0][k][i] = p0; bb[1][k][i] = p1; }
    }
    __syncthreads();

    // ---- routing iter 1 (softmax -> einsum -> squash -> b update)
    if (t < 64) {                          // lanes 0-31: pair0, 32-63: pair1
        const int p = t >> 5, ii = t & 31;
        float m = bb[p][0][ii];
        #pragma unroll
        for (int kk = 1; kk < NC; ++kk) m = fmaxf(m, bb[p][kk][ii]);
        float e[NC], s = 0.0f;
        #pragma unroll
        for (int kk = 0; kk < NC; ++kk) { e[kk] = __expf(bb[p][kk][ii] - m); s += e[kk]; }
        float si = 1.0f / s;
        #pragma unroll
        for (int kk = 0; kk < NC; ++kk) cc[p][kk][ii] = e[kk] * si;
    }
    __syncthreads();

    out0 = 0.0f; out1 = 0.0f;
    #pragma unroll
    for (int i = 0; i < IC; ++i) {
        out0 = fmaf(cc[0][k][i], r0[i], out0);
        out1 = fmaf(cc[1][k][i], r1[i], out1);
    }
    out0 = squash16(out0);
    out1 = squash16(out1);
    #pragma unroll
    for (int i = 0; i < IC; ++i) {
        float p0 = reduce16(out0 * r0[i]);
        float p1 = reduce16(out1 * r1[i]);
        if (d == 0) { bb[0][k][i] += p0; bb[1][k][i] += p1; }
    }
    __syncthreads();

    // ---- routing iter 2 (softmax -> einsum -> store, no squash)
    if (t < 64) {
        const int p = t >> 5, ii = t & 31;
        float m = bb[p][0][ii];
        #pragma unroll
        for (int kk = 1; kk < NC; ++kk) m = fmaxf(m, bb[p][kk][ii]);
        float e[NC], s = 0.0f;
        #pragma unroll
        for (int kk = 0; kk < NC; ++kk) { e[kk] = __expf(bb[p][kk][ii] - m); s += e[kk]; }
        float si = 1.0f / s;
        #pragma unroll
        for (int kk = 0; kk < NC; ++kk) cc[p][kk][ii] = e[kk] * si;
    }
    __syncthreads();

    out0 = 0.0f; out1 = 0.0f;
    #pragma unroll
    for (int i = 0; i < IC; ++i) {
        out0 = fmaf(cc[0][k][i], r0[i], out0);
        out1 = fmaf(cc[1][k][i], r1[i], out1);
    }

    outp[(size_t)pair0 * O + t]       = out0;   // coalesced
    outp[(size_t)(pair0 + 1) * O + t] = out1;
}

extern "C" void kernel_launch(void* const* d_in, const int* in_sizes, int n_in,
                              void* d_out, int out_size, void* d_ws, size_t ws_size,
                              hipStream_t stream) {
    const float* inp = (const float*)d_in[0];   // [32,128,32,16] fp32
    const float* W   = (const float*)d_in[1];   // [32,16,256]   fp32
    float* outp      = (float*)d_out;           // [32,128,16,16] fp32

    const int npairs = 32 * 128;                // B*N = 4096
    dim3 grid(npairs / 2), block(256);
    hipLaunchKernelGGL(capsule_routing_kernel, grid, block, 0, stream,
                       inp, W, outp);
}